// Round 18
// baseline (124.968 us; speedup 1.0000x reference)
//
#include <hip/hip_runtime.h>
#include <hip/hip_bf16.h>

typedef __attribute__((ext_vector_type(4)))  float f32x4;
typedef __attribute__((ext_vector_type(16))) float f32x16;
typedef __attribute__((ext_vector_type(8)))  short short8;
typedef __attribute__((ext_vector_type(4)))  short short4v;

__device__ __forceinline__ short f2bf(float f) {
  union { float f; unsigned u; } x; x.f = f;
  unsigned r = (x.u + 0x7FFFu + ((x.u >> 16) & 1u)) >> 16;
  return (short)r;
}
__device__ __forceinline__ unsigned cvtpk(float lo, float hi) {
  unsigned r;
  asm("v_cvt_pk_bf16_f32 %0, %1, %2" : "=v"(r) : "v"(lo), "v"(hi));
  return r;
}

// ---------------- cast f32 -> bf16, vectorized x4 ----------------
__global__ __launch_bounds__(256) void k_cast(const float* __restrict__ in,
                                              short* __restrict__ out, int n4) {
  int i = blockIdx.x * 256 + threadIdx.x;
  if (i >= n4) return;
  f32x4 v = ((const f32x4*)in)[i];
  short4v s;
  s[0] = f2bf(v[0]); s[1] = f2bf(v[1]); s[2] = f2bf(v[2]); s[3] = f2bf(v[3]);
  ((short4v*)out)[i] = s;
}

// ---------------- pack w_q/w_k/w_v -> WqkvT bf16 [3072][1024] ----------------
__global__ __launch_bounds__(256) void k_pack(const float* __restrict__ wq,
                                              const float* __restrict__ wk,
                                              const float* __restrict__ wv,
                                              short* __restrict__ WT) {
  int nt = blockIdx.x, et = blockIdx.y, sel = blockIdx.z;
  const float* w = sel == 0 ? wq : (sel == 1 ? wk : wv);
  __shared__ float tile[64][65];
  int tid = threadIdx.x;
  int cl = tid & 63, rw = tid >> 6;
#pragma unroll
  for (int j = 0; j < 16; ++j) {
    int el = j * 4 + rw;
    tile[el][cl] = w[(size_t)(et * 64 + el) * 1024 + nt * 64 + cl];
  }
  __syncthreads();
#pragma unroll
  for (int j = 0; j < 16; ++j) {
    int nl = j * 4 + rw;
    int n = sel * 1024 + nt * 64 + nl;
    WT[(size_t)n * 1024 + et * 64 + cl] = f2bf(tile[cl][nl]);
  }
}

// ---------------- GEMM C[M][N] = A[M][K] * B^T[N][K], bf16 in, f32 acc ----------------
// Reg-staged prefetch + vectorized V^T epilogue + XCD-chunked block swizzle:
// each XCD owns a contiguous run of N-columns so its B-panel stays L2-resident.
// EPI==0: scatter Q(*0.125*log2e)/K -> [BH][2048][64], V -> V^T [BH][64][2048]; EPI==1: f32 out
template <int EPI>
__global__ __launch_bounds__(256) void k_gemm(const short* __restrict__ A,
                                              const short* __restrict__ B,
                                              short* __restrict__ Qo, short* __restrict__ Ko,
                                              short* __restrict__ Vo, float* __restrict__ out,
                                              int M, int N, int K) {
  __shared__ short As[128][40];
  __shared__ short Bs[128][40];
  int tid = threadIdx.x;

  // XCD-chunked bijective swizzle (nwg % 8 == 0 for both GEMMs):
  // chunk of nwg/8 consecutive remapped ids -> one XCD; column-major decomposition
  // so each XCD walks all M-rows of a few N-columns (B-panel L2-resident).
  int bid = blockIdx.y * gridDim.x + blockIdx.x;
  int cpx = (gridDim.x * gridDim.y) >> 3;
  int swz = (bid & 7) * cpx + (bid >> 3);
  int bxi = swz / gridDim.y;
  int byi = swz % gridDim.y;
  int bm = byi * 128, bn = bxi * 128;

  int wid = tid >> 6, lane = tid & 63;
  int wm = (wid >> 1) * 64, wn = (wid & 1) * 64;
  int lg = lane >> 4, lr = lane & 15;
  f32x4 acc[4][4] = {};

  int sr = tid >> 2, sc = tid & 3;
  const short* Ar0 = A + (size_t)(bm + sr) * K;
  const short* Ar1 = A + (size_t)(bm + sr + 64) * K;
  const short* Br0 = B + (size_t)(bn + sr) * K;
  const short* Br1 = B + (size_t)(bn + sr + 64) * K;

  short8 pa0 = *(const short8*)&Ar0[sc * 8];
  short8 pa1 = *(const short8*)&Ar1[sc * 8];
  short8 pb0 = *(const short8*)&Br0[sc * 8];
  short8 pb1 = *(const short8*)&Br1[sc * 8];

  int nk = K >> 5;
  for (int kt = 0; kt < nk; ++kt) {
    __syncthreads();
    *(short8*)&As[sr][sc * 8] = pa0;
    *(short8*)&As[sr + 64][sc * 8] = pa1;
    *(short8*)&Bs[sr][sc * 8] = pb0;
    *(short8*)&Bs[sr + 64][sc * 8] = pb1;
    if (kt + 1 < nk) {
      int ko = (kt + 1) * 32;
      pa0 = *(const short8*)&Ar0[ko + sc * 8];
      pa1 = *(const short8*)&Ar1[ko + sc * 8];
      pb0 = *(const short8*)&Br0[ko + sc * 8];
      pb1 = *(const short8*)&Br1[ko + sc * 8];
    }
    __syncthreads();
    short8 af[4], bf_[4];
#pragma unroll
    for (int mt = 0; mt < 4; ++mt)
      af[mt] = *(const short8*)&As[wm + mt * 16 + lr][lg * 8];
#pragma unroll
    for (int ntl = 0; ntl < 4; ++ntl)
      bf_[ntl] = *(const short8*)&Bs[wn + ntl * 16 + lr][lg * 8];
#pragma unroll
    for (int mt = 0; mt < 4; ++mt)
#pragma unroll
      for (int ntl = 0; ntl < 4; ++ntl)
        acc[mt][ntl] = __builtin_amdgcn_mfma_f32_16x16x32_bf16(af[mt], bf_[ntl], acc[mt][ntl], 0, 0, 0);
  }

#pragma unroll
  for (int mt = 0; mt < 4; ++mt)
#pragma unroll
    for (int ntl = 0; ntl < 4; ++ntl) {
      int m0 = bm + wm + mt * 16 + lg * 4;
      int n = bn + wn + ntl * 16 + lr;
      if (EPI == 0) {
        int b = m0 >> 11, s0 = m0 & 2047;
        int sel = n >> 10, hk = n & 1023;
        int h = hk >> 6, kd = hk & 63;
        if (sel == 0) {
#pragma unroll
          for (int rr = 0; rr < 4; ++rr)
            Qo[((size_t)(b * 16 + h) * 2048 + s0 + rr) * 64 + kd] =
                f2bf(acc[mt][ntl][rr] * 0.18033688011112042f);  // 0.125*log2e
        } else if (sel == 1) {
#pragma unroll
          for (int rr = 0; rr < 4; ++rr)
            Ko[((size_t)(b * 16 + h) * 2048 + s0 + rr) * 64 + kd] = f2bf(acc[mt][ntl][rr]);
        } else {
          short4v v4;
#pragma unroll
          for (int rr = 0; rr < 4; ++rr) v4[rr] = f2bf(acc[mt][ntl][rr]);
          *(short4v*)&Vo[((size_t)(b * 16 + h) * 64 + kd) * 2048 + s0] = v4;  // V^T, 8B store
        }
      } else {
#pragma unroll
        for (int rr = 0; rr < 4; ++rr)
          out[(size_t)(m0 + rr) * 1024 + n] = acc[mt][ntl][rr];
      }
    }
}

// ---------------- causal flash attention: no-max softmax + paired-tile ILP ----------------
// (round-14/16 verified config: reg-staged prefetch, ~58 us)
// Q,K: [32][2048][64] bf16 (Q pre-scaled 1/8*log2e). VT: [32][64][2048]. O: [2][2048][1024] bf16.
__global__ __launch_bounds__(128, 2) void k_attn(const short* __restrict__ Q,
                                                 const short* __restrict__ K,
                                                 const short* __restrict__ VT,
                                                 short* __restrict__ O) {
  const int S = 2048;
  int bh = blockIdx.x;
  int g = 31 - blockIdx.y;

  int tid = threadIdx.x;
  int wid = tid >> 6, lane = tid & 63;
  int hi = lane >> 5, ln = lane & 31;
  int qw = 2 * g + wid;
  int q_g = qw * 32 + ln;
  int npair = g + 1;

  __shared__ short Ks[2][2][32][64];
  __shared__ short Vs[2][2][64][32];

  const short* Qb = Q + (size_t)bh * S * 64;
  const short* Kb = K + (size_t)bh * S * 64;
  const short* Vb = VT + (size_t)bh * 64 * S;

  // Q fragments: B[k=d][col=q]
  short8 qf[4];
#pragma unroll
  for (int ds = 0; ds < 4; ++ds)
    qf[ds] = *(const short8*)&Qb[(size_t)q_g * 64 + ds * 16 + hi * 8];

  // staging thread mapping (block-wide)
  int kr = tid >> 2, kcb = tid & 3;          // K: row 0..31, chunks kcb, kcb+4
  int vd = tid >> 1, vcb = tid & 1;          // V: row d 0..63, chunks vcb, vcb+2
  const short* kgp = Kb + (size_t)kr * 64;
  const short* vgp = Vb + (size_t)vd * S;

  // prefetch pair 0 (tiles 0,1)
  short8 ka0 = *(const short8*)&kgp[kcb * 8];
  short8 ka1 = *(const short8*)&kgp[(kcb + 4) * 8];
  short8 kb0 = *(const short8*)&kgp[2048 + kcb * 8];
  short8 kb1 = *(const short8*)&kgp[2048 + (kcb + 4) * 8];
  short8 va0 = *(const short8*)&vgp[vcb * 8];
  short8 va1 = *(const short8*)&vgp[(vcb + 2) * 8];
  short8 vb0 = *(const short8*)&vgp[32 + vcb * 8];
  short8 vb1 = *(const short8*)&vgp[32 + (vcb + 2) * 8];

  f32x16 acoA = {}, acoB = {};
  float l = 0.f;

  for (int p = 0; p < npair; ++p) {
    int pb = p & 1;
    // stage both tiles of the pair (swizzled)
    *(short8*)&Ks[pb][0][kr][(kcb ^ (kr & 7)) * 8]       = ka0;
    *(short8*)&Ks[pb][0][kr][((kcb + 4) ^ (kr & 7)) * 8] = ka1;
    *(short8*)&Ks[pb][1][kr][(kcb ^ (kr & 7)) * 8]       = kb0;
    *(short8*)&Ks[pb][1][kr][((kcb + 4) ^ (kr & 7)) * 8] = kb1;
    *(short8*)&Vs[pb][0][vd][(vcb ^ (vd & 3)) * 8]       = va0;
    *(short8*)&Vs[pb][0][vd][((vcb + 2) ^ (vd & 3)) * 8] = va1;
    *(short8*)&Vs[pb][1][vd][(vcb ^ (vd & 3)) * 8]       = vb0;
    *(short8*)&Vs[pb][1][vd][((vcb + 2) ^ (vd & 3)) * 8] = vb1;
    // prefetch next pair (latency hides under compute)
    if (p + 1 < npair) {
      size_t ko0 = (size_t)(2 * p + 2) * 2048, ko1 = (size_t)(2 * p + 3) * 2048;
      size_t vo0 = (size_t)(2 * p + 2) * 32,   vo1 = (size_t)(2 * p + 3) * 32;
      ka0 = *(const short8*)&kgp[ko0 + kcb * 8];
      ka1 = *(const short8*)&kgp[ko0 + (kcb + 4) * 8];
      kb0 = *(const short8*)&kgp[ko1 + kcb * 8];
      kb1 = *(const short8*)&kgp[ko1 + (kcb + 4) * 8];
      va0 = *(const short8*)&vgp[vo0 + vcb * 8];
      va1 = *(const short8*)&vgp[vo0 + (vcb + 2) * 8];
      vb0 = *(const short8*)&vgp[vo1 + vcb * 8];
      vb1 = *(const short8*)&vgp[vo1 + (vcb + 2) * 8];
    }
    __syncthreads();

    int t0 = 2 * p, t1 = 2 * p + 1;

    // K fragments for both tiles
    short8 kc00 = *(const short8*)&Ks[pb][0][ln][((0 + hi) ^ (ln & 7)) * 8];
    short8 kc01 = *(const short8*)&Ks[pb][0][ln][((2 + hi) ^ (ln & 7)) * 8];
    short8 kc02 = *(const short8*)&Ks[pb][0][ln][((4 + hi) ^ (ln & 7)) * 8];
    short8 kc03 = *(const short8*)&Ks[pb][0][ln][((6 + hi) ^ (ln & 7)) * 8];
    short8 kc10 = *(const short8*)&Ks[pb][1][ln][((0 + hi) ^ (ln & 7)) * 8];
    short8 kc11 = *(const short8*)&Ks[pb][1][ln][((2 + hi) ^ (ln & 7)) * 8];
    short8 kc12 = *(const short8*)&Ks[pb][1][ln][((4 + hi) ^ (ln & 7)) * 8];
    short8 kc13 = *(const short8*)&Ks[pb][1][ln][((6 + hi) ^ (ln & 7)) * 8];

    f32x16 sa0 = {}, sa1 = {};
    __builtin_amdgcn_s_setprio(1);
    sa0 = __builtin_amdgcn_mfma_f32_32x32x16_bf16(kc00, qf[0], sa0, 0, 0, 0);
    sa1 = __builtin_amdgcn_mfma_f32_32x32x16_bf16(kc10, qf[0], sa1, 0, 0, 0);
    sa0 = __builtin_amdgcn_mfma_f32_32x32x16_bf16(kc01, qf[1], sa0, 0, 0, 0);
    sa1 = __builtin_amdgcn_mfma_f32_32x32x16_bf16(kc11, qf[1], sa1, 0, 0, 0);
    sa0 = __builtin_amdgcn_mfma_f32_32x32x16_bf16(kc02, qf[2], sa0, 0, 0, 0);
    sa1 = __builtin_amdgcn_mfma_f32_32x32x16_bf16(kc12, qf[2], sa1, 0, 0, 0);
    sa0 = __builtin_amdgcn_mfma_f32_32x32x16_bf16(kc03, qf[3], sa0, 0, 0, 0);
    sa1 = __builtin_amdgcn_mfma_f32_32x32x16_bf16(kc13, qf[3], sa1, 0, 0, 0);
    __builtin_amdgcn_s_setprio(0);

    // causal mask (t==qw: diagonal; t>qw: fully masked -> tile contributes nothing)
    if (t0 >= qw) {
#pragma unroll
      for (int r = 0; r < 16; ++r) {
        int kv_g = t0 * 32 + (r & 3) + 8 * (r >> 2) + 4 * hi;
        if (kv_g > q_g) sa0[r] = -1e30f;
      }
    }
    if (t1 >= qw) {
#pragma unroll
      for (int r = 0; r < 16; ++r) {
        int kv_g = t1 * 32 + (r & 3) + 8 * (r >> 2) + 4 * hi;
        if (kv_g > q_g) sa1[r] = -1e30f;
      }
    }

    // no-max softmax, both tiles (independent chains)
    float p0[16], p1[16];
#pragma unroll
    for (int r = 0; r < 16; ++r) p0[r] = exp2f(sa0[r]);
#pragma unroll
    for (int r = 0; r < 16; ++r) p1[r] = exp2f(sa1[r]);
    {
      float s00 = (p0[0] + p0[1]) + (p0[2] + p0[3]);
      float s01 = (p0[4] + p0[5]) + (p0[6] + p0[7]);
      float s02 = (p0[8] + p0[9]) + (p0[10] + p0[11]);
      float s03 = (p0[12] + p0[13]) + (p0[14] + p0[15]);
      float s10 = (p1[0] + p1[1]) + (p1[2] + p1[3]);
      float s11 = (p1[4] + p1[5]) + (p1[6] + p1[7]);
      float s12 = (p1[8] + p1[9]) + (p1[10] + p1[11]);
      float s13 = (p1[12] + p1[13]) + (p1[14] + p1[15]);
      l += ((s00 + s01) + (s02 + s03)) + ((s10 + s11) + (s12 + s13));
    }

    // pack + PV tile 0
    {
      short8 v00 = *(const short8*)&Vs[pb][0][ln][((0 + hi) ^ (ln & 3)) * 8];
      short8 v01 = *(const short8*)&Vs[pb][0][ln][((2 + hi) ^ (ln & 3)) * 8];
      short8 v10 = *(const short8*)&Vs[pb][0][32 + ln][((0 + hi) ^ (ln & 3)) * 8];
      short8 v11 = *(const short8*)&Vs[pb][0][32 + ln][((2 + hi) ^ (ln & 3)) * 8];
#pragma unroll
      for (int s = 0; s < 2; ++s) {
        unsigned c0 = cvtpk(p0[8 * s + 0], p0[8 * s + 1]);
        unsigned c1 = cvtpk(p0[8 * s + 2], p0[8 * s + 3]);
        unsigned c2 = cvtpk(p0[8 * s + 4], p0[8 * s + 5]);
        unsigned c3 = cvtpk(p0[8 * s + 6], p0[8 * s + 7]);
        unsigned pc0 = (unsigned)__shfl_xor((int)c0, 32);
        unsigned pc1 = (unsigned)__shfl_xor((int)c1, 32);
        unsigned pc2 = (unsigned)__shfl_xor((int)c2, 32);
        unsigned pc3 = (unsigned)__shfl_xor((int)c3, 32);
        union { unsigned u[4]; short8 v; } pbv;
        pbv.u[0] = hi ? pc2 : c0;
        pbv.u[1] = hi ? pc3 : c1;
        pbv.u[2] = hi ? c2 : pc0;
        pbv.u[3] = hi ? c3 : pc1;
        __builtin_amdgcn_s_setprio(1);
        if (s == 0) {
          acoA = __builtin_amdgcn_mfma_f32_32x32x16_bf16(v00, pbv.v, acoA, 0, 0, 0);
          acoB = __builtin_amdgcn_mfma_f32_32x32x16_bf16(v10, pbv.v, acoB, 0, 0, 0);
        } else {
          acoA = __builtin_amdgcn_mfma_f32_32x32x16_bf16(v01, pbv.v, acoA, 0, 0, 0);
          acoB = __builtin_amdgcn_mfma_f32_32x32x16_bf16(v11, pbv.v, acoB, 0, 0, 0);
        }
        __builtin_amdgcn_s_setprio(0);
      }
    }
    // pack + PV tile 1
    {
      short8 v00 = *(const short8*)&Vs[pb][1][ln][((0 + hi) ^ (ln & 3)) * 8];
      short8 v01 = *(const short8*)&Vs[pb][1][ln][((2 + hi) ^ (ln & 3)) * 8];
      short8 v10 = *(const short8*)&Vs[pb][1][32 + ln][((0 + hi) ^ (ln & 3)) * 8];
      short8 v11 = *(const short8*)&Vs[pb][1][32 + ln][((2 + hi) ^ (ln & 3)) * 8];
#pragma unroll
      for (int s = 0; s < 2; ++s) {
        unsigned c0 = cvtpk(p1[8 * s + 0], p1[8 * s + 1]);
        unsigned c1 = cvtpk(p1[8 * s + 2], p1[8 * s + 3]);
        unsigned c2 = cvtpk(p1[8 * s + 4], p1[8 * s + 5]);
        unsigned c3 = cvtpk(p1[8 * s + 6], p1[8 * s + 7]);
        unsigned pc0 = (unsigned)__shfl_xor((int)c0, 32);
        unsigned pc1 = (unsigned)__shfl_xor((int)c1, 32);
        unsigned pc2 = (unsigned)__shfl_xor((int)c2, 32);
        unsigned pc3 = (unsigned)__shfl_xor((int)c3, 32);
        union { unsigned u[4]; short8 v; } pbv;
        pbv.u[0] = hi ? pc2 : c0;
        pbv.u[1] = hi ? pc3 : c1;
        pbv.u[2] = hi ? c2 : pc0;
        pbv.u[3] = hi ? c3 : pc1;
        __builtin_amdgcn_s_setprio(1);
        if (s == 0) {
          acoA = __builtin_amdgcn_mfma_f32_32x32x16_bf16(v00, pbv.v, acoA, 0, 0, 0);
          acoB = __builtin_amdgcn_mfma_f32_32x32x16_bf16(v10, pbv.v, acoB, 0, 0, 0);
        } else {
          acoA = __builtin_amdgcn_mfma_f32_32x32x16_bf16(v01, pbv.v, acoA, 0, 0, 0);
          acoB = __builtin_amdgcn_mfma_f32_32x32x16_bf16(v11, pbv.v, acoB, 0, 0, 0);
        }
        __builtin_amdgcn_s_setprio(0);
      }
    }
  }

  // merge the lane^32 pair's l once, normalize, store
  l += __shfl_xor(l, 32);
  float rl = 1.f / l;
  int b = bh >> 4, h = bh & 15;
  size_t obase = ((size_t)b * 2048 + q_g) * 1024 + h * 64;
#pragma unroll
  for (int g4 = 0; g4 < 4; ++g4) {
    int d0 = 8 * g4 + 4 * hi;
    *(unsigned*)&O[obase + d0]          = cvtpk(acoA[4 * g4] * rl, acoA[4 * g4 + 1] * rl);
    *(unsigned*)&O[obase + d0 + 2]      = cvtpk(acoA[4 * g4 + 2] * rl, acoA[4 * g4 + 3] * rl);
    *(unsigned*)&O[obase + 32 + d0]     = cvtpk(acoB[4 * g4] * rl, acoB[4 * g4 + 1] * rl);
    *(unsigned*)&O[obase + 32 + d0 + 2] = cvtpk(acoB[4 * g4 + 2] * rl, acoB[4 * g4 + 3] * rl);
  }
}

extern "C" void kernel_launch(void* const* d_in, const int* in_sizes, int n_in,
                              void* d_out, int out_size, void* d_ws, size_t ws_size,
                              hipStream_t stream) {
  const float* x  = (const float*)d_in[0];
  const float* wq = (const float*)d_in[1];
  const float* wk = (const float*)d_in[2];
  const float* wv = (const float*)d_in[3];
  const float* wo = (const float*)d_in[4];
  float* out = (float*)d_out;
  char* ws = (char*)d_ws;

  short* x_bf  = (short*)(ws);                       // 8 MB
  short* WqkvT = (short*)(ws + ((size_t)8 << 20));   // 6 MB
  short* wo_bf = (short*)(ws + ((size_t)14 << 20));  // 2 MB
  short* Qb    = (short*)(ws + ((size_t)16 << 20));  // 8 MB
  short* Kb    = (short*)(ws + ((size_t)24 << 20));  // 8 MB
  short* Vt    = (short*)(ws + ((size_t)32 << 20));  // 8 MB (V^T)
  short* Ob    = (short*)(ws + ((size_t)40 << 20));  // 8 MB

  k_cast<<<4096, 256, 0, stream>>>(x, x_bf, 1048576);
  k_cast<<<1024, 256, 0, stream>>>(wo, wo_bf, 262144);
  k_pack<<<dim3(16, 16, 3), 256, 0, stream>>>(wq, wk, wv, WqkvT);
  k_gemm<0><<<dim3(24, 32), 256, 0, stream>>>(x_bf, WqkvT, Qb, Kb, Vt, nullptr, 4096, 3072, 1024);
  k_attn<<<dim3(32, 32), 128, 0, stream>>>(Qb, Kb, Vt, Ob);
  k_gemm<1><<<dim3(8, 32), 256, 0, stream>>>(Ob, wo_bf, nullptr, nullptr, nullptr, out, 4096, 1024, 1024);
}

// Round 19
// 124.723 us; speedup vs baseline: 1.0020x; 1.0020x over previous
//
#include <hip/hip_runtime.h>
#include <hip/hip_bf16.h>

typedef __attribute__((ext_vector_type(4)))  float f32x4;
typedef __attribute__((ext_vector_type(16))) float f32x16;
typedef __attribute__((ext_vector_type(8)))  short short8;
typedef __attribute__((ext_vector_type(4)))  short short4v;

__device__ __forceinline__ short f2bf(float f) {
  union { float f; unsigned u; } x; x.f = f;
  unsigned r = (x.u + 0x7FFFu + ((x.u >> 16) & 1u)) >> 16;
  return (short)r;
}
__device__ __forceinline__ unsigned cvtpk(float lo, float hi) {
  unsigned r;
  asm("v_cvt_pk_bf16_f32 %0, %1, %2" : "=v"(r) : "v"(lo), "v"(hi));
  return r;
}

// ---------------- cast f32 -> bf16, vectorized x4 ----------------
__global__ __launch_bounds__(256) void k_cast(const float* __restrict__ in,
                                              short* __restrict__ out, int n4) {
  int i = blockIdx.x * 256 + threadIdx.x;
  if (i >= n4) return;
  f32x4 v = ((const f32x4*)in)[i];
  short4v s;
  s[0] = f2bf(v[0]); s[1] = f2bf(v[1]); s[2] = f2bf(v[2]); s[3] = f2bf(v[3]);
  ((short4v*)out)[i] = s;
}

// ---------------- pack w_q/w_k/w_v -> WqkvT bf16 [3072][1024] ----------------
__global__ __launch_bounds__(256) void k_pack(const float* __restrict__ wq,
                                              const float* __restrict__ wk,
                                              const float* __restrict__ wv,
                                              short* __restrict__ WT) {
  int nt = blockIdx.x, et = blockIdx.y, sel = blockIdx.z;
  const float* w = sel == 0 ? wq : (sel == 1 ? wk : wv);
  __shared__ float tile[64][65];
  int tid = threadIdx.x;
  int cl = tid & 63, rw = tid >> 6;
#pragma unroll
  for (int j = 0; j < 16; ++j) {
    int el = j * 4 + rw;
    tile[el][cl] = w[(size_t)(et * 64 + el) * 1024 + nt * 64 + cl];
  }
  __syncthreads();
#pragma unroll
  for (int j = 0; j < 16; ++j) {
    int nl = j * 4 + rw;
    int n = sel * 1024 + nt * 64 + nl;
    WT[(size_t)n * 1024 + et * 64 + cl] = f2bf(tile[cl][nl]);
  }
}

// ---------------- GEMM C[M][N] = A[M][K] * B^T[N][K], bf16 in, f32 acc ----------------
// Reg-staged prefetch; vectorized V^T epilogue (8B stores) — round-16 verified config.
// EPI==0: scatter Q(*0.125*log2e)/K -> [BH][2048][64], V -> V^T [BH][64][2048]; EPI==1: f32 out
template <int EPI>
__global__ __launch_bounds__(256) void k_gemm(const short* __restrict__ A,
                                              const short* __restrict__ B,
                                              short* __restrict__ Qo, short* __restrict__ Ko,
                                              short* __restrict__ Vo, float* __restrict__ out,
                                              int M, int N, int K) {
  __shared__ short As[128][40];
  __shared__ short Bs[128][40];
  int tid = threadIdx.x;
  int bm = blockIdx.y * 128, bn = blockIdx.x * 128;
  int wid = tid >> 6, lane = tid & 63;
  int wm = (wid >> 1) * 64, wn = (wid & 1) * 64;
  int lg = lane >> 4, lr = lane & 15;
  f32x4 acc[4][4] = {};

  int sr = tid >> 2, sc = tid & 3;
  const short* Ar0 = A + (size_t)(bm + sr) * K;
  const short* Ar1 = A + (size_t)(bm + sr + 64) * K;
  const short* Br0 = B + (size_t)(bn + sr) * K;
  const short* Br1 = B + (size_t)(bn + sr + 64) * K;

  short8 pa0 = *(const short8*)&Ar0[sc * 8];
  short8 pa1 = *(const short8*)&Ar1[sc * 8];
  short8 pb0 = *(const short8*)&Br0[sc * 8];
  short8 pb1 = *(const short8*)&Br1[sc * 8];

  int nk = K >> 5;
  for (int kt = 0; kt < nk; ++kt) {
    __syncthreads();
    *(short8*)&As[sr][sc * 8] = pa0;
    *(short8*)&As[sr + 64][sc * 8] = pa1;
    *(short8*)&Bs[sr][sc * 8] = pb0;
    *(short8*)&Bs[sr + 64][sc * 8] = pb1;
    if (kt + 1 < nk) {
      int ko = (kt + 1) * 32;
      pa0 = *(const short8*)&Ar0[ko + sc * 8];
      pa1 = *(const short8*)&Ar1[ko + sc * 8];
      pb0 = *(const short8*)&Br0[ko + sc * 8];
      pb1 = *(const short8*)&Br1[ko + sc * 8];
    }
    __syncthreads();
    short8 af[4], bf_[4];
#pragma unroll
    for (int mt = 0; mt < 4; ++mt)
      af[mt] = *(const short8*)&As[wm + mt * 16 + lr][lg * 8];
#pragma unroll
    for (int ntl = 0; ntl < 4; ++ntl)
      bf_[ntl] = *(const short8*)&Bs[wn + ntl * 16 + lr][lg * 8];
#pragma unroll
    for (int mt = 0; mt < 4; ++mt)
#pragma unroll
      for (int ntl = 0; ntl < 4; ++ntl)
        acc[mt][ntl] = __builtin_amdgcn_mfma_f32_16x16x32_bf16(af[mt], bf_[ntl], acc[mt][ntl], 0, 0, 0);
  }

#pragma unroll
  for (int mt = 0; mt < 4; ++mt)
#pragma unroll
    for (int ntl = 0; ntl < 4; ++ntl) {
      int m0 = bm + wm + mt * 16 + lg * 4;
      int n = bn + wn + ntl * 16 + lr;
      if (EPI == 0) {
        int b = m0 >> 11, s0 = m0 & 2047;
        int sel = n >> 10, hk = n & 1023;
        int h = hk >> 6, kd = hk & 63;
        if (sel == 0) {
#pragma unroll
          for (int rr = 0; rr < 4; ++rr)
            Qo[((size_t)(b * 16 + h) * 2048 + s0 + rr) * 64 + kd] =
                f2bf(acc[mt][ntl][rr] * 0.18033688011112042f);  // 0.125*log2e
        } else if (sel == 1) {
#pragma unroll
          for (int rr = 0; rr < 4; ++rr)
            Ko[((size_t)(b * 16 + h) * 2048 + s0 + rr) * 64 + kd] = f2bf(acc[mt][ntl][rr]);
        } else {
          short4v v4;
#pragma unroll
          for (int rr = 0; rr < 4; ++rr) v4[rr] = f2bf(acc[mt][ntl][rr]);
          *(short4v*)&Vo[((size_t)(b * 16 + h) * 64 + kd) * 2048 + s0] = v4;  // V^T, 8B store
        }
      } else {
#pragma unroll
        for (int rr = 0; rr < 4; ++rr)
          out[(size_t)(m0 + rr) * 1024 + n] = acc[mt][ntl][rr];
      }
    }
}

// ---------------- causal flash attention: no-max softmax + paired-tile ILP ----------------
// (round-14/16 structure; pack exchange halved: 2 shfls instead of 4 per s-group —
//  each lane pre-selects exactly what its lane^32 partner needs.)
// Q,K: [32][2048][64] bf16 (Q pre-scaled 1/8*log2e). VT: [32][64][2048]. O: [2][2048][1024] bf16.
__global__ __launch_bounds__(128, 2) void k_attn(const short* __restrict__ Q,
                                                 const short* __restrict__ K,
                                                 const short* __restrict__ VT,
                                                 short* __restrict__ O) {
  const int S = 2048;
  int bh = blockIdx.x;
  int g = 31 - blockIdx.y;

  int tid = threadIdx.x;
  int wid = tid >> 6, lane = tid & 63;
  int hi = lane >> 5, ln = lane & 31;
  int qw = 2 * g + wid;
  int q_g = qw * 32 + ln;
  int npair = g + 1;

  __shared__ short Ks[2][2][32][64];
  __shared__ short Vs[2][2][64][32];

  const short* Qb = Q + (size_t)bh * S * 64;
  const short* Kb = K + (size_t)bh * S * 64;
  const short* Vb = VT + (size_t)bh * 64 * S;

  // Q fragments: B[k=d][col=q]
  short8 qf[4];
#pragma unroll
  for (int ds = 0; ds < 4; ++ds)
    qf[ds] = *(const short8*)&Qb[(size_t)q_g * 64 + ds * 16 + hi * 8];

  // staging thread mapping (block-wide)
  int kr = tid >> 2, kcb = tid & 3;          // K: row 0..31, chunks kcb, kcb+4
  int vd = tid >> 1, vcb = tid & 1;          // V: row d 0..63, chunks vcb, vcb+2
  const short* kgp = Kb + (size_t)kr * 64;
  const short* vgp = Vb + (size_t)vd * S;

  // prefetch pair 0 (tiles 0,1)
  short8 ka0 = *(const short8*)&kgp[kcb * 8];
  short8 ka1 = *(const short8*)&kgp[(kcb + 4) * 8];
  short8 kb0 = *(const short8*)&kgp[2048 + kcb * 8];
  short8 kb1 = *(const short8*)&kgp[2048 + (kcb + 4) * 8];
  short8 va0 = *(const short8*)&vgp[vcb * 8];
  short8 va1 = *(const short8*)&vgp[(vcb + 2) * 8];
  short8 vb0 = *(const short8*)&vgp[32 + vcb * 8];
  short8 vb1 = *(const short8*)&vgp[32 + (vcb + 2) * 8];

  f32x16 acoA = {}, acoB = {};
  float l = 0.f;

  for (int p = 0; p < npair; ++p) {
    int pb = p & 1;
    // stage both tiles of the pair (swizzled)
    *(short8*)&Ks[pb][0][kr][(kcb ^ (kr & 7)) * 8]       = ka0;
    *(short8*)&Ks[pb][0][kr][((kcb + 4) ^ (kr & 7)) * 8] = ka1;
    *(short8*)&Ks[pb][1][kr][(kcb ^ (kr & 7)) * 8]       = kb0;
    *(short8*)&Ks[pb][1][kr][((kcb + 4) ^ (kr & 7)) * 8] = kb1;
    *(short8*)&Vs[pb][0][vd][(vcb ^ (vd & 3)) * 8]       = va0;
    *(short8*)&Vs[pb][0][vd][((vcb + 2) ^ (vd & 3)) * 8] = va1;
    *(short8*)&Vs[pb][1][vd][(vcb ^ (vd & 3)) * 8]       = vb0;
    *(short8*)&Vs[pb][1][vd][((vcb + 2) ^ (vd & 3)) * 8] = vb1;
    // prefetch next pair (latency hides under compute)
    if (p + 1 < npair) {
      size_t ko0 = (size_t)(2 * p + 2) * 2048, ko1 = (size_t)(2 * p + 3) * 2048;
      size_t vo0 = (size_t)(2 * p + 2) * 32,   vo1 = (size_t)(2 * p + 3) * 32;
      ka0 = *(const short8*)&kgp[ko0 + kcb * 8];
      ka1 = *(const short8*)&kgp[ko0 + (kcb + 4) * 8];
      kb0 = *(const short8*)&kgp[ko1 + kcb * 8];
      kb1 = *(const short8*)&kgp[ko1 + (kcb + 4) * 8];
      va0 = *(const short8*)&vgp[vo0 + vcb * 8];
      va1 = *(const short8*)&vgp[vo0 + (vcb + 2) * 8];
      vb0 = *(const short8*)&vgp[vo1 + vcb * 8];
      vb1 = *(const short8*)&vgp[vo1 + (vcb + 2) * 8];
    }
    __syncthreads();

    int t0 = 2 * p, t1 = 2 * p + 1;

    // K fragments for both tiles
    short8 kc00 = *(const short8*)&Ks[pb][0][ln][((0 + hi) ^ (ln & 7)) * 8];
    short8 kc01 = *(const short8*)&Ks[pb][0][ln][((2 + hi) ^ (ln & 7)) * 8];
    short8 kc02 = *(const short8*)&Ks[pb][0][ln][((4 + hi) ^ (ln & 7)) * 8];
    short8 kc03 = *(const short8*)&Ks[pb][0][ln][((6 + hi) ^ (ln & 7)) * 8];
    short8 kc10 = *(const short8*)&Ks[pb][1][ln][((0 + hi) ^ (ln & 7)) * 8];
    short8 kc11 = *(const short8*)&Ks[pb][1][ln][((2 + hi) ^ (ln & 7)) * 8];
    short8 kc12 = *(const short8*)&Ks[pb][1][ln][((4 + hi) ^ (ln & 7)) * 8];
    short8 kc13 = *(const short8*)&Ks[pb][1][ln][((6 + hi) ^ (ln & 7)) * 8];

    f32x16 sa0 = {}, sa1 = {};
    __builtin_amdgcn_s_setprio(1);
    sa0 = __builtin_amdgcn_mfma_f32_32x32x16_bf16(kc00, qf[0], sa0, 0, 0, 0);
    sa1 = __builtin_amdgcn_mfma_f32_32x32x16_bf16(kc10, qf[0], sa1, 0, 0, 0);
    sa0 = __builtin_amdgcn_mfma_f32_32x32x16_bf16(kc01, qf[1], sa0, 0, 0, 0);
    sa1 = __builtin_amdgcn_mfma_f32_32x32x16_bf16(kc11, qf[1], sa1, 0, 0, 0);
    sa0 = __builtin_amdgcn_mfma_f32_32x32x16_bf16(kc02, qf[2], sa0, 0, 0, 0);
    sa1 = __builtin_amdgcn_mfma_f32_32x32x16_bf16(kc12, qf[2], sa1, 0, 0, 0);
    sa0 = __builtin_amdgcn_mfma_f32_32x32x16_bf16(kc03, qf[3], sa0, 0, 0, 0);
    sa1 = __builtin_amdgcn_mfma_f32_32x32x16_bf16(kc13, qf[3], sa1, 0, 0, 0);
    __builtin_amdgcn_s_setprio(0);

    // causal mask (t==qw: diagonal; t>qw: fully masked -> tile contributes nothing)
    if (t0 >= qw) {
#pragma unroll
      for (int r = 0; r < 16; ++r) {
        int kv_g = t0 * 32 + (r & 3) + 8 * (r >> 2) + 4 * hi;
        if (kv_g > q_g) sa0[r] = -1e30f;
      }
    }
    if (t1 >= qw) {
#pragma unroll
      for (int r = 0; r < 16; ++r) {
        int kv_g = t1 * 32 + (r & 3) + 8 * (r >> 2) + 4 * hi;
        if (kv_g > q_g) sa1[r] = -1e30f;
      }
    }

    // no-max softmax, both tiles (independent chains)
    float p0[16], p1[16];
#pragma unroll
    for (int r = 0; r < 16; ++r) p0[r] = exp2f(sa0[r]);
#pragma unroll
    for (int r = 0; r < 16; ++r) p1[r] = exp2f(sa1[r]);
    {
      float s00 = (p0[0] + p0[1]) + (p0[2] + p0[3]);
      float s01 = (p0[4] + p0[5]) + (p0[6] + p0[7]);
      float s02 = (p0[8] + p0[9]) + (p0[10] + p0[11]);
      float s03 = (p0[12] + p0[13]) + (p0[14] + p0[15]);
      float s10 = (p1[0] + p1[1]) + (p1[2] + p1[3]);
      float s11 = (p1[4] + p1[5]) + (p1[6] + p1[7]);
      float s12 = (p1[8] + p1[9]) + (p1[10] + p1[11]);
      float s13 = (p1[12] + p1[13]) + (p1[14] + p1[15]);
      l += ((s00 + s01) + (s02 + s03)) + ((s10 + s11) + (s12 + s13));
    }

    // pack + PV tile 0 (2 shfls per s-group: send exactly what the partner needs)
    {
      short8 v00 = *(const short8*)&Vs[pb][0][ln][((0 + hi) ^ (ln & 3)) * 8];
      short8 v01 = *(const short8*)&Vs[pb][0][ln][((2 + hi) ^ (ln & 3)) * 8];
      short8 v10 = *(const short8*)&Vs[pb][0][32 + ln][((0 + hi) ^ (ln & 3)) * 8];
      short8 v11 = *(const short8*)&Vs[pb][0][32 + ln][((2 + hi) ^ (ln & 3)) * 8];
#pragma unroll
      for (int s = 0; s < 2; ++s) {
        unsigned c0 = cvtpk(p0[8 * s + 0], p0[8 * s + 1]);
        unsigned c1 = cvtpk(p0[8 * s + 2], p0[8 * s + 3]);
        unsigned c2 = cvtpk(p0[8 * s + 4], p0[8 * s + 5]);
        unsigned c3 = cvtpk(p0[8 * s + 6], p0[8 * s + 7]);
        unsigned r1 = (unsigned)__shfl_xor((int)(hi ? c0 : c2), 32);
        unsigned r2 = (unsigned)__shfl_xor((int)(hi ? c1 : c3), 32);
        union { unsigned u[4]; short8 v; } pbv;
        pbv.u[0] = hi ? r1 : c0;
        pbv.u[1] = hi ? r2 : c1;
        pbv.u[2] = hi ? c2 : r1;
        pbv.u[3] = hi ? c3 : r2;
        __builtin_amdgcn_s_setprio(1);
        if (s == 0) {
          acoA = __builtin_amdgcn_mfma_f32_32x32x16_bf16(v00, pbv.v, acoA, 0, 0, 0);
          acoB = __builtin_amdgcn_mfma_f32_32x32x16_bf16(v10, pbv.v, acoB, 0, 0, 0);
        } else {
          acoA = __builtin_amdgcn_mfma_f32_32x32x16_bf16(v01, pbv.v, acoA, 0, 0, 0);
          acoB = __builtin_amdgcn_mfma_f32_32x32x16_bf16(v11, pbv.v, acoB, 0, 0, 0);
        }
        __builtin_amdgcn_s_setprio(0);
      }
    }
    // pack + PV tile 1
    {
      short8 v00 = *(const short8*)&Vs[pb][1][ln][((0 + hi) ^ (ln & 3)) * 8];
      short8 v01 = *(const short8*)&Vs[pb][1][ln][((2 + hi) ^ (ln & 3)) * 8];
      short8 v10 = *(const short8*)&Vs[pb][1][32 + ln][((0 + hi) ^ (ln & 3)) * 8];
      short8 v11 = *(const short8*)&Vs[pb][1][32 + ln][((2 + hi) ^ (ln & 3)) * 8];
#pragma unroll
      for (int s = 0; s < 2; ++s) {
        unsigned c0 = cvtpk(p1[8 * s + 0], p1[8 * s + 1]);
        unsigned c1 = cvtpk(p1[8 * s + 2], p1[8 * s + 3]);
        unsigned c2 = cvtpk(p1[8 * s + 4], p1[8 * s + 5]);
        unsigned c3 = cvtpk(p1[8 * s + 6], p1[8 * s + 7]);
        unsigned r1 = (unsigned)__shfl_xor((int)(hi ? c0 : c2), 32);
        unsigned r2 = (unsigned)__shfl_xor((int)(hi ? c1 : c3), 32);
        union { unsigned u[4]; short8 v; } pbv;
        pbv.u[0] = hi ? r1 : c0;
        pbv.u[1] = hi ? r2 : c1;
        pbv.u[2] = hi ? c2 : r1;
        pbv.u[3] = hi ? c3 : r2;
        __builtin_amdgcn_s_setprio(1);
        if (s == 0) {
          acoA = __builtin_amdgcn_mfma_f32_32x32x16_bf16(v00, pbv.v, acoA, 0, 0, 0);
          acoB = __builtin_amdgcn_mfma_f32_32x32x16_bf16(v10, pbv.v, acoB, 0, 0, 0);
        } else {
          acoA = __builtin_amdgcn_mfma_f32_32x32x16_bf16(v01, pbv.v, acoA, 0, 0, 0);
          acoB = __builtin_amdgcn_mfma_f32_32x32x16_bf16(v11, pbv.v, acoB, 0, 0, 0);
        }
        __builtin_amdgcn_s_setprio(0);
      }
    }
  }

  // merge the lane^32 pair's l once, normalize, store
  l += __shfl_xor(l, 32);
  float rl = 1.f / l;
  int b = bh >> 4, h = bh & 15;
  size_t obase = ((size_t)b * 2048 + q_g) * 1024 + h * 64;
#pragma unroll
  for (int g4 = 0; g4 < 4; ++g4) {
    int d0 = 8 * g4 + 4 * hi;
    *(unsigned*)&O[obase + d0]          = cvtpk(acoA[4 * g4] * rl, acoA[4 * g4 + 1] * rl);
    *(unsigned*)&O[obase + d0 + 2]      = cvtpk(acoA[4 * g4 + 2] * rl, acoA[4 * g4 + 3] * rl);
    *(unsigned*)&O[obase + 32 + d0]     = cvtpk(acoB[4 * g4] * rl, acoB[4 * g4 + 1] * rl);
    *(unsigned*)&O[obase + 32 + d0 + 2] = cvtpk(acoB[4 * g4 + 2] * rl, acoB[4 * g4 + 3] * rl);
  }
}

extern "C" void kernel_launch(void* const* d_in, const int* in_sizes, int n_in,
                              void* d_out, int out_size, void* d_ws, size_t ws_size,
                              hipStream_t stream) {
  const float* x  = (const float*)d_in[0];
  const float* wq = (const float*)d_in[1];
  const float* wk = (const float*)d_in[2];
  const float* wv = (const float*)d_in[3];
  const float* wo = (const float*)d_in[4];
  float* out = (float*)d_out;
  char* ws = (char*)d_ws;

  short* x_bf  = (short*)(ws);                       // 8 MB
  short* WqkvT = (short*)(ws + ((size_t)8 << 20));   // 6 MB
  short* wo_bf = (short*)(ws + ((size_t)14 << 20));  // 2 MB
  short* Qb    = (short*)(ws + ((size_t)16 << 20));  // 8 MB
  short* Kb    = (short*)(ws + ((size_t)24 << 20));  // 8 MB
  short* Vt    = (short*)(ws + ((size_t)32 << 20));  // 8 MB (V^T)
  short* Ob    = (short*)(ws + ((size_t)40 << 20));  // 8 MB

  k_cast<<<4096, 256, 0, stream>>>(x, x_bf, 1048576);
  k_cast<<<1024, 256, 0, stream>>>(wo, wo_bf, 262144);
  k_pack<<<dim3(16, 16, 3), 256, 0, stream>>>(wq, wk, wv, WqkvT);
  k_gemm<0><<<dim3(24, 32), 256, 0, stream>>>(x_bf, WqkvT, Qb, Kb, Vt, nullptr, 4096, 3072, 1024);
  k_attn<<<dim3(32, 32), 128, 0, stream>>>(Qb, Kb, Vt, Ob);
  k_gemm<1><<<dim3(8, 32), 256, 0, stream>>>(Ob, wo_bf, nullptr, nullptr, nullptr, out, 4096, 1024, 1024);
}

// Round 20
// 122.737 us; speedup vs baseline: 1.0182x; 1.0162x over previous
//
#include <hip/hip_runtime.h>
#include <hip/hip_bf16.h>

typedef __attribute__((ext_vector_type(4)))  float f32x4;
typedef __attribute__((ext_vector_type(16))) float f32x16;
typedef __attribute__((ext_vector_type(8)))  short short8;
typedef __attribute__((ext_vector_type(4)))  short short4v;

__device__ __forceinline__ short f2bf(float f) {
  union { float f; unsigned u; } x; x.f = f;
  unsigned r = (x.u + 0x7FFFu + ((x.u >> 16) & 1u)) >> 16;
  return (short)r;
}
__device__ __forceinline__ unsigned cvtpk(float lo, float hi) {
  unsigned r;
  asm("v_cvt_pk_bf16_f32 %0, %1, %2" : "=v"(r) : "v"(lo), "v"(hi));
  return r;
}

// ---------------- cast f32 -> bf16, vectorized x4 ----------------
__global__ __launch_bounds__(256) void k_cast(const float* __restrict__ in,
                                              short* __restrict__ out, int n4) {
  int i = blockIdx.x * 256 + threadIdx.x;
  if (i >= n4) return;
  f32x4 v = ((const f32x4*)in)[i];
  short4v s;
  s[0] = f2bf(v[0]); s[1] = f2bf(v[1]); s[2] = f2bf(v[2]); s[3] = f2bf(v[3]);
  ((short4v*)out)[i] = s;
}

// ---------------- pack w_q/w_k/w_v -> WqkvT bf16 [3072][1024] ----------------
__global__ __launch_bounds__(256) void k_pack(const float* __restrict__ wq,
                                              const float* __restrict__ wk,
                                              const float* __restrict__ wv,
                                              short* __restrict__ WT) {
  int nt = blockIdx.x, et = blockIdx.y, sel = blockIdx.z;
  const float* w = sel == 0 ? wq : (sel == 1 ? wk : wv);
  __shared__ float tile[64][65];
  int tid = threadIdx.x;
  int cl = tid & 63, rw = tid >> 6;
#pragma unroll
  for (int j = 0; j < 16; ++j) {
    int el = j * 4 + rw;
    tile[el][cl] = w[(size_t)(et * 64 + el) * 1024 + nt * 64 + cl];
  }
  __syncthreads();
#pragma unroll
  for (int j = 0; j < 16; ++j) {
    int nl = j * 4 + rw;
    int n = sel * 1024 + nt * 64 + nl;
    WT[(size_t)n * 1024 + et * 64 + cl] = f2bf(tile[cl][nl]);
  }
}

// ---------------- GEMM C[M][N] = A[M][K] * B^T[N][K], bf16 in, f32 acc ----------------
// Reg-staged prefetch; vectorized V^T epilogue (8B stores) — verified-fastest config.
// EPI==0: scatter Q(*0.125*log2e)/K -> [BH][2048][64], V -> V^T [BH][64][2048]; EPI==1: f32 out
template <int EPI>
__global__ __launch_bounds__(256) void k_gemm(const short* __restrict__ A,
                                              const short* __restrict__ B,
                                              short* __restrict__ Qo, short* __restrict__ Ko,
                                              short* __restrict__ Vo, float* __restrict__ out,
                                              int M, int N, int K) {
  __shared__ short As[128][40];
  __shared__ short Bs[128][40];
  int tid = threadIdx.x;
  int bm = blockIdx.y * 128, bn = blockIdx.x * 128;
  int wid = tid >> 6, lane = tid & 63;
  int wm = (wid >> 1) * 64, wn = (wid & 1) * 64;
  int lg = lane >> 4, lr = lane & 15;
  f32x4 acc[4][4] = {};

  int sr = tid >> 2, sc = tid & 3;
  const short* Ar0 = A + (size_t)(bm + sr) * K;
  const short* Ar1 = A + (size_t)(bm + sr + 64) * K;
  const short* Br0 = B + (size_t)(bn + sr) * K;
  const short* Br1 = B + (size_t)(bn + sr + 64) * K;

  short8 pa0 = *(const short8*)&Ar0[sc * 8];
  short8 pa1 = *(const short8*)&Ar1[sc * 8];
  short8 pb0 = *(const short8*)&Br0[sc * 8];
  short8 pb1 = *(const short8*)&Br1[sc * 8];

  int nk = K >> 5;
  for (int kt = 0; kt < nk; ++kt) {
    __syncthreads();
    *(short8*)&As[sr][sc * 8] = pa0;
    *(short8*)&As[sr + 64][sc * 8] = pa1;
    *(short8*)&Bs[sr][sc * 8] = pb0;
    *(short8*)&Bs[sr + 64][sc * 8] = pb1;
    if (kt + 1 < nk) {
      int ko = (kt + 1) * 32;
      pa0 = *(const short8*)&Ar0[ko + sc * 8];
      pa1 = *(const short8*)&Ar1[ko + sc * 8];
      pb0 = *(const short8*)&Br0[ko + sc * 8];
      pb1 = *(const short8*)&Br1[ko + sc * 8];
    }
    __syncthreads();
    short8 af[4], bf_[4];
#pragma unroll
    for (int mt = 0; mt < 4; ++mt)
      af[mt] = *(const short8*)&As[wm + mt * 16 + lr][lg * 8];
#pragma unroll
    for (int ntl = 0; ntl < 4; ++ntl)
      bf_[ntl] = *(const short8*)&Bs[wn + ntl * 16 + lr][lg * 8];
#pragma unroll
    for (int mt = 0; mt < 4; ++mt)
#pragma unroll
      for (int ntl = 0; ntl < 4; ++ntl)
        acc[mt][ntl] = __builtin_amdgcn_mfma_f32_16x16x32_bf16(af[mt], bf_[ntl], acc[mt][ntl], 0, 0, 0);
  }

#pragma unroll
  for (int mt = 0; mt < 4; ++mt)
#pragma unroll
    for (int ntl = 0; ntl < 4; ++ntl) {
      int m0 = bm + wm + mt * 16 + lg * 4;
      int n = bn + wn + ntl * 16 + lr;
      if (EPI == 0) {
        int b = m0 >> 11, s0 = m0 & 2047;
        int sel = n >> 10, hk = n & 1023;
        int h = hk >> 6, kd = hk & 63;
        if (sel == 0) {
#pragma unroll
          for (int rr = 0; rr < 4; ++rr)
            Qo[((size_t)(b * 16 + h) * 2048 + s0 + rr) * 64 + kd] =
                f2bf(acc[mt][ntl][rr] * 0.18033688011112042f);  // 0.125*log2e
        } else if (sel == 1) {
#pragma unroll
          for (int rr = 0; rr < 4; ++rr)
            Ko[((size_t)(b * 16 + h) * 2048 + s0 + rr) * 64 + kd] = f2bf(acc[mt][ntl][rr]);
        } else {
          short4v v4;
#pragma unroll
          for (int rr = 0; rr < 4; ++rr) v4[rr] = f2bf(acc[mt][ntl][rr]);
          *(short4v*)&Vo[((size_t)(b * 16 + h) * 64 + kd) * 2048 + s0] = v4;  // V^T, 8B store
        }
      } else {
#pragma unroll
        for (int rr = 0; rr < 4; ++rr)
          out[(size_t)(m0 + rr) * 1024 + n] = acc[mt][ntl][rr];
      }
    }
}

// ---------------- causal flash attention: no-max softmax + paired-tile ILP ----------------
// (round-14/16 verified config: reg-staged prefetch, ~58 us)
// Q,K: [32][2048][64] bf16 (Q pre-scaled 1/8*log2e). VT: [32][64][2048]. O: [2][2048][1024] bf16.
__global__ __launch_bounds__(128, 2) void k_attn(const short* __restrict__ Q,
                                                 const short* __restrict__ K,
                                                 const short* __restrict__ VT,
                                                 short* __restrict__ O) {
  const int S = 2048;
  int bh = blockIdx.x;
  int g = 31 - blockIdx.y;

  int tid = threadIdx.x;
  int wid = tid >> 6, lane = tid & 63;
  int hi = lane >> 5, ln = lane & 31;
  int qw = 2 * g + wid;
  int q_g = qw * 32 + ln;
  int npair = g + 1;

  __shared__ short Ks[2][2][32][64];
  __shared__ short Vs[2][2][64][32];

  const short* Qb = Q + (size_t)bh * S * 64;
  const short* Kb = K + (size_t)bh * S * 64;
  const short* Vb = VT + (size_t)bh * 64 * S;

  // Q fragments: B[k=d][col=q]
  short8 qf[4];
#pragma unroll
  for (int ds = 0; ds < 4; ++ds)
    qf[ds] = *(const short8*)&Qb[(size_t)q_g * 64 + ds * 16 + hi * 8];

  // staging thread mapping (block-wide)
  int kr = tid >> 2, kcb = tid & 3;          // K: row 0..31, chunks kcb, kcb+4
  int vd = tid >> 1, vcb = tid & 1;          // V: row d 0..63, chunks vcb, vcb+2
  const short* kgp = Kb + (size_t)kr * 64;
  const short* vgp = Vb + (size_t)vd * S;

  // prefetch pair 0 (tiles 0,1)
  short8 ka0 = *(const short8*)&kgp[kcb * 8];
  short8 ka1 = *(const short8*)&kgp[(kcb + 4) * 8];
  short8 kb0 = *(const short8*)&kgp[2048 + kcb * 8];
  short8 kb1 = *(const short8*)&kgp[2048 + (kcb + 4) * 8];
  short8 va0 = *(const short8*)&vgp[vcb * 8];
  short8 va1 = *(const short8*)&vgp[(vcb + 2) * 8];
  short8 vb0 = *(const short8*)&vgp[32 + vcb * 8];
  short8 vb1 = *(const short8*)&vgp[32 + (vcb + 2) * 8];

  f32x16 acoA = {}, acoB = {};
  float l = 0.f;

  for (int p = 0; p < npair; ++p) {
    int pb = p & 1;
    // stage both tiles of the pair (swizzled)
    *(short8*)&Ks[pb][0][kr][(kcb ^ (kr & 7)) * 8]       = ka0;
    *(short8*)&Ks[pb][0][kr][((kcb + 4) ^ (kr & 7)) * 8] = ka1;
    *(short8*)&Ks[pb][1][kr][(kcb ^ (kr & 7)) * 8]       = kb0;
    *(short8*)&Ks[pb][1][kr][((kcb + 4) ^ (kr & 7)) * 8] = kb1;
    *(short8*)&Vs[pb][0][vd][(vcb ^ (vd & 3)) * 8]       = va0;
    *(short8*)&Vs[pb][0][vd][((vcb + 2) ^ (vd & 3)) * 8] = va1;
    *(short8*)&Vs[pb][1][vd][(vcb ^ (vd & 3)) * 8]       = vb0;
    *(short8*)&Vs[pb][1][vd][((vcb + 2) ^ (vd & 3)) * 8] = vb1;
    // prefetch next pair (latency hides under compute)
    if (p + 1 < npair) {
      size_t ko0 = (size_t)(2 * p + 2) * 2048, ko1 = (size_t)(2 * p + 3) * 2048;
      size_t vo0 = (size_t)(2 * p + 2) * 32,   vo1 = (size_t)(2 * p + 3) * 32;
      ka0 = *(const short8*)&kgp[ko0 + kcb * 8];
      ka1 = *(const short8*)&kgp[ko0 + (kcb + 4) * 8];
      kb0 = *(const short8*)&kgp[ko1 + kcb * 8];
      kb1 = *(const short8*)&kgp[ko1 + (kcb + 4) * 8];
      va0 = *(const short8*)&vgp[vo0 + vcb * 8];
      va1 = *(const short8*)&vgp[vo0 + (vcb + 2) * 8];
      vb0 = *(const short8*)&vgp[vo1 + vcb * 8];
      vb1 = *(const short8*)&vgp[vo1 + (vcb + 2) * 8];
    }
    __syncthreads();

    int t0 = 2 * p, t1 = 2 * p + 1;

    // K fragments for both tiles
    short8 kc00 = *(const short8*)&Ks[pb][0][ln][((0 + hi) ^ (ln & 7)) * 8];
    short8 kc01 = *(const short8*)&Ks[pb][0][ln][((2 + hi) ^ (ln & 7)) * 8];
    short8 kc02 = *(const short8*)&Ks[pb][0][ln][((4 + hi) ^ (ln & 7)) * 8];
    short8 kc03 = *(const short8*)&Ks[pb][0][ln][((6 + hi) ^ (ln & 7)) * 8];
    short8 kc10 = *(const short8*)&Ks[pb][1][ln][((0 + hi) ^ (ln & 7)) * 8];
    short8 kc11 = *(const short8*)&Ks[pb][1][ln][((2 + hi) ^ (ln & 7)) * 8];
    short8 kc12 = *(const short8*)&Ks[pb][1][ln][((4 + hi) ^ (ln & 7)) * 8];
    short8 kc13 = *(const short8*)&Ks[pb][1][ln][((6 + hi) ^ (ln & 7)) * 8];

    f32x16 sa0 = {}, sa1 = {};
    __builtin_amdgcn_s_setprio(1);
    sa0 = __builtin_amdgcn_mfma_f32_32x32x16_bf16(kc00, qf[0], sa0, 0, 0, 0);
    sa1 = __builtin_amdgcn_mfma_f32_32x32x16_bf16(kc10, qf[0], sa1, 0, 0, 0);
    sa0 = __builtin_amdgcn_mfma_f32_32x32x16_bf16(kc01, qf[1], sa0, 0, 0, 0);
    sa1 = __builtin_amdgcn_mfma_f32_32x32x16_bf16(kc11, qf[1], sa1, 0, 0, 0);
    sa0 = __builtin_amdgcn_mfma_f32_32x32x16_bf16(kc02, qf[2], sa0, 0, 0, 0);
    sa1 = __builtin_amdgcn_mfma_f32_32x32x16_bf16(kc12, qf[2], sa1, 0, 0, 0);
    sa0 = __builtin_amdgcn_mfma_f32_32x32x16_bf16(kc03, qf[3], sa0, 0, 0, 0);
    sa1 = __builtin_amdgcn_mfma_f32_32x32x16_bf16(kc13, qf[3], sa1, 0, 0, 0);
    __builtin_amdgcn_s_setprio(0);

    // causal mask (t==qw: diagonal; t>qw: fully masked -> tile contributes nothing)
    if (t0 >= qw) {
#pragma unroll
      for (int r = 0; r < 16; ++r) {
        int kv_g = t0 * 32 + (r & 3) + 8 * (r >> 2) + 4 * hi;
        if (kv_g > q_g) sa0[r] = -1e30f;
      }
    }
    if (t1 >= qw) {
#pragma unroll
      for (int r = 0; r < 16; ++r) {
        int kv_g = t1 * 32 + (r & 3) + 8 * (r >> 2) + 4 * hi;
        if (kv_g > q_g) sa1[r] = -1e30f;
      }
    }

    // no-max softmax, both tiles (independent chains)
    float p0[16], p1[16];
#pragma unroll
    for (int r = 0; r < 16; ++r) p0[r] = exp2f(sa0[r]);
#pragma unroll
    for (int r = 0; r < 16; ++r) p1[r] = exp2f(sa1[r]);
    {
      float s00 = (p0[0] + p0[1]) + (p0[2] + p0[3]);
      float s01 = (p0[4] + p0[5]) + (p0[6] + p0[7]);
      float s02 = (p0[8] + p0[9]) + (p0[10] + p0[11]);
      float s03 = (p0[12] + p0[13]) + (p0[14] + p0[15]);
      float s10 = (p1[0] + p1[1]) + (p1[2] + p1[3]);
      float s11 = (p1[4] + p1[5]) + (p1[6] + p1[7]);
      float s12 = (p1[8] + p1[9]) + (p1[10] + p1[11]);
      float s13 = (p1[12] + p1[13]) + (p1[14] + p1[15]);
      l += ((s00 + s01) + (s02 + s03)) + ((s10 + s11) + (s12 + s13));
    }

    // pack + PV tile 0
    {
      short8 v00 = *(const short8*)&Vs[pb][0][ln][((0 + hi) ^ (ln & 3)) * 8];
      short8 v01 = *(const short8*)&Vs[pb][0][ln][((2 + hi) ^ (ln & 3)) * 8];
      short8 v10 = *(const short8*)&Vs[pb][0][32 + ln][((0 + hi) ^ (ln & 3)) * 8];
      short8 v11 = *(const short8*)&Vs[pb][0][32 + ln][((2 + hi) ^ (ln & 3)) * 8];
#pragma unroll
      for (int s = 0; s < 2; ++s) {
        unsigned c0 = cvtpk(p0[8 * s + 0], p0[8 * s + 1]);
        unsigned c1 = cvtpk(p0[8 * s + 2], p0[8 * s + 3]);
        unsigned c2 = cvtpk(p0[8 * s + 4], p0[8 * s + 5]);
        unsigned c3 = cvtpk(p0[8 * s + 6], p0[8 * s + 7]);
        unsigned pc0 = (unsigned)__shfl_xor((int)c0, 32);
        unsigned pc1 = (unsigned)__shfl_xor((int)c1, 32);
        unsigned pc2 = (unsigned)__shfl_xor((int)c2, 32);
        unsigned pc3 = (unsigned)__shfl_xor((int)c3, 32);
        union { unsigned u[4]; short8 v; } pbv;
        pbv.u[0] = hi ? pc2 : c0;
        pbv.u[1] = hi ? pc3 : c1;
        pbv.u[2] = hi ? c2 : pc0;
        pbv.u[3] = hi ? c3 : pc1;
        __builtin_amdgcn_s_setprio(1);
        if (s == 0) {
          acoA = __builtin_amdgcn_mfma_f32_32x32x16_bf16(v00, pbv.v, acoA, 0, 0, 0);
          acoB = __builtin_amdgcn_mfma_f32_32x32x16_bf16(v10, pbv.v, acoB, 0, 0, 0);
        } else {
          acoA = __builtin_amdgcn_mfma_f32_32x32x16_bf16(v01, pbv.v, acoA, 0, 0, 0);
          acoB = __builtin_amdgcn_mfma_f32_32x32x16_bf16(v11, pbv.v, acoB, 0, 0, 0);
        }
        __builtin_amdgcn_s_setprio(0);
      }
    }
    // pack + PV tile 1
    {
      short8 v00 = *(const short8*)&Vs[pb][1][ln][((0 + hi) ^ (ln & 3)) * 8];
      short8 v01 = *(const short8*)&Vs[pb][1][ln][((2 + hi) ^ (ln & 3)) * 8];
      short8 v10 = *(const short8*)&Vs[pb][1][32 + ln][((0 + hi) ^ (ln & 3)) * 8];
      short8 v11 = *(const short8*)&Vs[pb][1][32 + ln][((2 + hi) ^ (ln & 3)) * 8];
#pragma unroll
      for (int s = 0; s < 2; ++s) {
        unsigned c0 = cvtpk(p1[8 * s + 0], p1[8 * s + 1]);
        unsigned c1 = cvtpk(p1[8 * s + 2], p1[8 * s + 3]);
        unsigned c2 = cvtpk(p1[8 * s + 4], p1[8 * s + 5]);
        unsigned c3 = cvtpk(p1[8 * s + 6], p1[8 * s + 7]);
        unsigned pc0 = (unsigned)__shfl_xor((int)c0, 32);
        unsigned pc1 = (unsigned)__shfl_xor((int)c1, 32);
        unsigned pc2 = (unsigned)__shfl_xor((int)c2, 32);
        unsigned pc3 = (unsigned)__shfl_xor((int)c3, 32);
        union { unsigned u[4]; short8 v; } pbv;
        pbv.u[0] = hi ? pc2 : c0;
        pbv.u[1] = hi ? pc3 : c1;
        pbv.u[2] = hi ? c2 : pc0;
        pbv.u[3] = hi ? c3 : pc1;
        __builtin_amdgcn_s_setprio(1);
        if (s == 0) {
          acoA = __builtin_amdgcn_mfma_f32_32x32x16_bf16(v00, pbv.v, acoA, 0, 0, 0);
          acoB = __builtin_amdgcn_mfma_f32_32x32x16_bf16(v10, pbv.v, acoB, 0, 0, 0);
        } else {
          acoA = __builtin_amdgcn_mfma_f32_32x32x16_bf16(v01, pbv.v, acoA, 0, 0, 0);
          acoB = __builtin_amdgcn_mfma_f32_32x32x16_bf16(v11, pbv.v, acoB, 0, 0, 0);
        }
        __builtin_amdgcn_s_setprio(0);
      }
    }
  }

  // merge the lane^32 pair's l once, normalize, store
  l += __shfl_xor(l, 32);
  float rl = 1.f / l;
  int b = bh >> 4, h = bh & 15;
  size_t obase = ((size_t)b * 2048 + q_g) * 1024 + h * 64;
#pragma unroll
  for (int g4 = 0; g4 < 4; ++g4) {
    int d0 = 8 * g4 + 4 * hi;
    *(unsigned*)&O[obase + d0]          = cvtpk(acoA[4 * g4] * rl, acoA[4 * g4 + 1] * rl);
    *(unsigned*)&O[obase + d0 + 2]      = cvtpk(acoA[4 * g4 + 2] * rl, acoA[4 * g4 + 3] * rl);
    *(unsigned*)&O[obase + 32 + d0]     = cvtpk(acoB[4 * g4] * rl, acoB[4 * g4 + 1] * rl);
    *(unsigned*)&O[obase + 32 + d0 + 2] = cvtpk(acoB[4 * g4 + 2] * rl, acoB[4 * g4 + 3] * rl);
  }
}

extern "C" void kernel_launch(void* const* d_in, const int* in_sizes, int n_in,
                              void* d_out, int out_size, void* d_ws, size_t ws_size,
                              hipStream_t stream) {
  const float* x  = (const float*)d_in[0];
  const float* wq = (const float*)d_in[1];
  const float* wk = (const float*)d_in[2];
  const float* wv = (const float*)d_in[3];
  const float* wo = (const float*)d_in[4];
  float* out = (float*)d_out;
  char* ws = (char*)d_ws;

  short* x_bf  = (short*)(ws);                       // 8 MB
  short* WqkvT = (short*)(ws + ((size_t)8 << 20));   // 6 MB
  short* wo_bf = (short*)(ws + ((size_t)14 << 20));  // 2 MB
  short* Qb    = (short*)(ws + ((size_t)16 << 20));  // 8 MB
  short* Kb    = (short*)(ws + ((size_t)24 << 20));  // 8 MB
  short* Vt    = (short*)(ws + ((size_t)32 << 20));  // 8 MB (V^T)
  short* Ob    = (short*)(ws + ((size_t)40 << 20));  // 8 MB

  k_cast<<<4096, 256, 0, stream>>>(x, x_bf, 1048576);
  k_cast<<<1024, 256, 0, stream>>>(wo, wo_bf, 262144);
  k_pack<<<dim3(16, 16, 3), 256, 0, stream>>>(wq, wk, wv, WqkvT);
  k_gemm<0><<<dim3(24, 32), 256, 0, stream>>>(x_bf, WqkvT, Qb, Kb, Vt, nullptr, 4096, 3072, 1024);
  k_attn<<<dim3(32, 32), 128, 0, stream>>>(Qb, Kb, Vt, Ob);
  k_gemm<1><<<dim3(8, 32), 256, 0, stream>>>(Ob, wo_bf, nullptr, nullptr, nullptr, out, 4096, 1024, 1024);
}